// Round 1
// baseline (259.547 us; speedup 1.0000x reference)
//
#include <hip/hip_runtime.h>
#include <hip/hip_bf16.h>
#include <math.h>

#define NN 4096
#define INDIM 45
#define HH 44
#define NHEAD 4
#define HD 11
#define NEDGE 131072
#define QT 8
#define NEGV (-1e9f)

__device__ __forceinline__ float warp_sum64(float v) {
    #pragma unroll
    for (int i = 32; i > 0; i >>= 1) v += __shfl_xor(v, i, 64);
    return v;
}
__device__ __forceinline__ float warp_max64(float v) {
    #pragma unroll
    for (int i = 32; i > 0; i >>= 1) v = fmaxf(v, __shfl_xor(v, i, 64));
    return v;
}

// ---------------- Kernel 1a: x = nf @ Wp + bp ----------------
__global__ void proj_in(const float* __restrict__ nf, const float* __restrict__ Wp,
                        const float* __restrict__ bp, float* __restrict__ x) {
    int idx = blockIdx.x * blockDim.x + threadIdx.x; // n*HH + j
    if (idx >= NN * HH) return;
    int n = idx / HH, j = idx % HH;
    const float* row = nf + n * INDIM;
    float acc = bp[j];
    #pragma unroll
    for (int k = 0; k < INDIM; ++k) acc += row[k] * Wp[k * HH + j];
    x[idx] = acc;
}

// ---------------- Kernel 1b: Q,K,V projections ----------------
// Q layout: [NHEAD][NN][HD] ; K,V layout: [NHEAD][HD][NN] (transposed for coalesced attn loads)
__global__ void proj_qkv(const float* __restrict__ x,
                         const float* __restrict__ Wq, const float* __restrict__ bq,
                         const float* __restrict__ Wk, const float* __restrict__ bk,
                         const float* __restrict__ Wv, const float* __restrict__ bv,
                         float* __restrict__ Qs, float* __restrict__ Ks, float* __restrict__ Vs) {
    int idx = blockIdx.x * blockDim.x + threadIdx.x; // n*HH + j
    if (idx >= NN * HH) return;
    int n = idx / HH, j = idx % HH;
    const float* row = x + n * HH;
    float aq = bq[j], ak = bk[j], av = bv[j];
    #pragma unroll
    for (int k = 0; k < HH; ++k) {
        float xv = row[k];
        aq += xv * Wq[k * HH + j];
        ak += xv * Wk[k * HH + j];
        av += xv * Wv[k * HH + j];
    }
    int h = j / HD, d = j % HD;
    Qs[(h * NN + n) * HD + d] = aq;
    Ks[((h * HD + d) * NN) + n] = ak;
    Vs[((h * HD + d) * NN) + n] = av;
}

// ---------------- Kernel 2: mask bitmap ----------------
__global__ void zero_mask(unsigned long long* __restrict__ p, int n64) {
    int i = blockIdx.x * blockDim.x + threadIdx.x;
    if (i < n64) p[i] = 0ull;
}
__global__ void build_mask(const int* __restrict__ ei, unsigned long long* __restrict__ mask) {
    int i = blockIdx.x * blockDim.x + threadIdx.x;
    if (i < NEDGE) {
        int r = ei[i];          // edge_index[0][i]  (query)
        int c = ei[NEDGE + i];  // edge_index[1][i]  (key)
        atomicOr(&mask[(size_t)r * (NN / 64) + (c >> 6)], 1ull << (c & 63));
    }
    if (i < NN) {
        atomicOr(&mask[(size_t)i * (NN / 64) + (i >> 6)], 1ull << (i & 63));
    }
}

// ---------------- Kernel 3: fused flash attention ----------------
// Block = 256 threads = 4 waves; wave w handles head w for QT queries.
// Lane j handles keys m = c*64 + j. Per-lane online softmax, butterfly merge.
__global__ __launch_bounds__(256, 2)
void attn_kernel(const float* __restrict__ Qs, const float* __restrict__ Ks,
                 const float* __restrict__ Vs, const float* __restrict__ temporal,
                 const unsigned long long* __restrict__ mask, float* __restrict__ att) {
    const int lane = threadIdx.x & 63;
    const int h = threadIdx.x >> 6;       // head
    const int n0 = blockIdx.x * QT;

    const float scale = 0.30151134457776363f;  // 1/sqrt(11)
    const float tbmul = 9.99990000099999f;     // 1/(0.1+1e-6)

    float qreg[QT][HD];
    #pragma unroll
    for (int q = 0; q < QT; ++q)
        #pragma unroll
        for (int d = 0; d < HD; ++d)
            qreg[q][d] = Qs[((size_t)h * NN + (n0 + q)) * HD + d];

    float mcur[QT], lsum[QT], oacc[QT][HD];
    #pragma unroll
    for (int q = 0; q < QT; ++q) {
        mcur[q] = -INFINITY;
        lsum[q] = 0.f;
        #pragma unroll
        for (int d = 0; d < HD; ++d) oacc[q][d] = 0.f;
    }

    for (int c = 0; c < NN / 64; ++c) {
        const int mm = c * 64 + lane;
        float kc[HD], vc[HD];
        #pragma unroll
        for (int d = 0; d < HD; ++d) kc[d] = Ks[((size_t)(h * HD + d)) * NN + mm];
        #pragma unroll
        for (int d = 0; d < HD; ++d) vc[d] = Vs[((size_t)(h * HD + d)) * NN + mm];

        #pragma unroll
        for (int q = 0; q < QT; ++q) {
            const int n = n0 + q;
            unsigned long long aw = mask[(size_t)n * (NN / 64) + c];
            float t = temporal[((size_t)n * NN + mm) * 2];
            float s = 0.f;
            #pragma unroll
            for (int d = 0; d < HD; ++d) s += qreg[q][d] * kc[d];
            s = s * scale - sqrtf(t * tbmul);
            bool allowed = (aw >> lane) & 1ull;
            s = allowed ? s : NEGV;
            if (s > mcur[q]) {
                float f = __expf(mcur[q] - s);
                lsum[q] *= f;
                #pragma unroll
                for (int d = 0; d < HD; ++d) oacc[q][d] *= f;
                mcur[q] = s;
            }
            float p = __expf(s - mcur[q]);
            lsum[q] += p;
            #pragma unroll
            for (int d = 0; d < HD; ++d) oacc[q][d] += p * vc[d];
        }
    }

    // cross-lane merge (exact log-sum-exp combine)
    #pragma unroll
    for (int q = 0; q < QT; ++q) {
        float M = warp_max64(mcur[q]);
        float sc = __expf(mcur[q] - M);
        float L = warp_sum64(lsum[q] * sc);
        float os[HD];
        #pragma unroll
        for (int d = 0; d < HD; ++d) os[d] = warp_sum64(oacc[q][d] * sc);
        if (lane == 0) {
            float inv = 1.f / L;
            #pragma unroll
            for (int d = 0; d < HD; ++d)
                att[(size_t)(n0 + q) * HH + h * HD + d] = os[d] * inv;
        }
    }
}

// ---------------- Kernel 4: out = att @ Wo + bo ----------------
__global__ void proj_out(const float* __restrict__ att, const float* __restrict__ Wo,
                         const float* __restrict__ bo, float* __restrict__ out) {
    int idx = blockIdx.x * blockDim.x + threadIdx.x; // n*HH + j
    if (idx >= NN * HH) return;
    int n = idx / HH, j = idx % HH;
    const float* row = att + n * HH;
    float a = bo[j];
    #pragma unroll
    for (int k = 0; k < HH; ++k) a += row[k] * Wo[k * HH + j];
    out[idx] = a;
}

extern "C" void kernel_launch(void* const* d_in, const int* in_sizes, int n_in,
                              void* d_out, int out_size, void* d_ws, size_t ws_size,
                              hipStream_t stream) {
    const float* nf       = (const float*)d_in[0];
    const int*   ei       = (const int*)d_in[1];
    const float* temporal = (const float*)d_in[2];
    const float* Wp = (const float*)d_in[3];
    const float* bp = (const float*)d_in[4];
    const float* Wq = (const float*)d_in[5];
    const float* bq = (const float*)d_in[6];
    const float* Wk = (const float*)d_in[7];
    const float* bk = (const float*)d_in[8];
    const float* Wv = (const float*)d_in[9];
    const float* bv = (const float*)d_in[10];
    const float* Wo = (const float*)d_in[11];
    const float* bo = (const float*)d_in[12];
    float* out = (float*)d_out;

    char* ws = (char*)d_ws;
    unsigned long long* mask = (unsigned long long*)ws;           // 2 MB (NN*NN bits)
    float* x   = (float*)(ws + (2u << 20));
    float* Qs  = x   + NN * HH;
    float* Ks  = Qs  + NN * HH;
    float* Vs  = Ks  + NN * HH;
    float* att = Vs  + NN * HH;

    const int nmask64 = NN * (NN / 64);   // 262144

    zero_mask<<<(nmask64 + 255) / 256, 256, 0, stream>>>(mask, nmask64);
    proj_in<<<(NN * HH + 255) / 256, 256, 0, stream>>>(nf, Wp, bp, x);
    proj_qkv<<<(NN * HH + 255) / 256, 256, 0, stream>>>(x, Wq, bq, Wk, bk, Wv, bv, Qs, Ks, Vs);
    build_mask<<<(NEDGE + 255) / 256, 256, 0, stream>>>(ei, mask);
    attn_kernel<<<NN / QT, 256, 0, stream>>>(Qs, Ks, Vs, temporal, mask, att);
    proj_out<<<(NN * HH + 255) / 256, 256, 0, stream>>>(att, Wo, bo, out);
}

// Round 2
// 52.389 us; speedup vs baseline: 4.9543x; 4.9543x over previous
//
#include <hip/hip_runtime.h>
#include <hip/hip_bf16.h>
#include <math.h>

#define NN 4096
#define INDIM 45
#define HH 44
#define NHEAD 4
#define HD 11
#define NEDGE 131072
#define CAP 512            // max allowed columns kept per row (mean ~33, >80 sigma headroom)
#define MASKW (NN / 64)    // 64-bit words per mask row

__device__ __forceinline__ float wsum64(float v) {
    #pragma unroll
    for (int i = 32; i > 0; i >>= 1) v += __shfl_xor(v, i, 64);
    return v;
}
__device__ __forceinline__ float wmax64(float v) {
    #pragma unroll
    for (int i = 32; i > 0; i >>= 1) v = fmaxf(v, __shfl_xor(v, i, 64));
    return v;
}

// ---------------- Kernel 1a: x = nf @ Wp + bp ----------------
__global__ __launch_bounds__(256)
void proj_in(const float* __restrict__ nf, const float* __restrict__ Wp,
             const float* __restrict__ bp, float* __restrict__ x) {
    int idx = blockIdx.x * blockDim.x + threadIdx.x; // n*HH + j
    if (idx >= NN * HH) return;
    int n = idx / HH, j = idx % HH;
    const float* row = nf + n * INDIM;
    float acc = bp[j];
    #pragma unroll
    for (int k = 0; k < INDIM; ++k) acc += row[k] * Wp[k * HH + j];
    x[idx] = acc;
}

// ---------------- Kernel 1b: Q,K,V projections, layout [N][44] ----------------
__global__ __launch_bounds__(256)
void proj_qkv(const float* __restrict__ x,
              const float* __restrict__ Wq, const float* __restrict__ bq,
              const float* __restrict__ Wk, const float* __restrict__ bk,
              const float* __restrict__ Wv, const float* __restrict__ bv,
              float* __restrict__ Qs, float* __restrict__ Ks, float* __restrict__ Vs) {
    int idx = blockIdx.x * blockDim.x + threadIdx.x; // n*HH + j
    if (idx >= NN * HH) return;
    int n = idx / HH, j = idx % HH;
    const float* row = x + n * HH;
    float aq = bq[j], ak = bk[j], av = bv[j];
    #pragma unroll
    for (int k = 0; k < HH; ++k) {
        float xv = row[k];
        aq += xv * Wq[k * HH + j];
        ak += xv * Wk[k * HH + j];
        av += xv * Wv[k * HH + j];
    }
    Qs[idx] = aq;
    Ks[idx] = ak;
    Vs[idx] = av;
}

// ---------------- Kernel 2: bitmask of ALLOWED pairs (edges + diagonal) ----------------
__global__ __launch_bounds__(256)
void build_mask(const int* __restrict__ ei, unsigned long long* __restrict__ mask) {
    int i = blockIdx.x * blockDim.x + threadIdx.x;
    if (i < NEDGE) {
        int r = ei[i];          // edge_index[0][i]  (query)
        int c = ei[NEDGE + i];  // edge_index[1][i]  (key)
        atomicOr(&mask[(size_t)r * MASKW + (c >> 6)], 1ull << (c & 63));
    }
    if (i < NN) {
        atomicOr(&mask[(size_t)i * MASKW + (i >> 6)], 1ull << (i & 63));
    }
}

// ---------------- Kernel 3: CSR build — one wave per row ----------------
// Lane l scans mask word l of the row; wave prefix-sum assigns compact slots.
__global__ __launch_bounds__(256)
void csr_build(const unsigned long long* __restrict__ mask,
               int* __restrict__ cnt, int* __restrict__ cols) {
    const int lane = threadIdx.x & 63;
    const int row = blockIdx.x * 4 + (threadIdx.x >> 6);
    if (row >= NN) return;
    unsigned long long w = mask[(size_t)row * MASKW + lane];
    int c = __popcll(w);
    int inc = c;
    #pragma unroll
    for (int i = 1; i < 64; i <<= 1) {
        int v = __shfl_up(inc, i, 64);
        if (lane >= i) inc += v;
    }
    int off = inc - c;               // exclusive prefix
    int total = __shfl(inc, 63, 64); // row degree
    int* dst = cols + (size_t)row * CAP;
    while (w) {
        int b = __builtin_ctzll(w);
        w &= w - 1;
        if (off < CAP) dst[off] = lane * 64 + b;
        ++off;
    }
    if (lane == 0) cnt[row] = total < CAP ? total : CAP;
}

// ---------------- Kernel 4: sparse attention + output projection ----------------
// Block = 256 threads = 4 waves = 4 heads, one query row n per block.
// Lane j handles allowed column cols[n][chunk*64+j]. Online softmax per lane,
// butterfly merge, LDS gather of the 44-dim attended row, fused @ Wo + bo.
__global__ __launch_bounds__(256)
void attn_out(const float* __restrict__ Qs, const float* __restrict__ Ks,
              const float* __restrict__ Vs, const float* __restrict__ temporal,
              const int* __restrict__ cnt, const int* __restrict__ cols,
              const float* __restrict__ Wo, const float* __restrict__ bo,
              float* __restrict__ out) {
    const int lane = threadIdx.x & 63;
    const int h = threadIdx.x >> 6;
    const int n = blockIdx.x;
    const float scale = 0.30151134457776363f;  // 1/sqrt(11)
    const float tbmul = 9.99990000099999f;     // 1/(0.1+1e-6)

    __shared__ float att_s[HH];

    const int deg = cnt[n];
    const int* clist = cols + (size_t)n * CAP;

    float qreg[HD];
    #pragma unroll
    for (int d = 0; d < HD; ++d) qreg[d] = Qs[(size_t)n * HH + h * HD + d];

    float mcur = -INFINITY, lsum = 0.f, oacc[HD];
    #pragma unroll
    for (int d = 0; d < HD; ++d) oacc[d] = 0.f;

    for (int base = 0; base < deg; base += 64) {
        const int j = base + lane;
        const bool active = j < deg;
        const int col = active ? clist[j] : 0;
        const float* kp = Ks + (size_t)col * HH + h * HD;
        const float* vp = Vs + (size_t)col * HH + h * HD;
        float t = temporal[((size_t)n * NN + col) * 2];
        float s = 0.f;
        #pragma unroll
        for (int d = 0; d < HD; ++d) s += qreg[d] * kp[d];
        s = s * scale - sqrtf(t * tbmul);
        if (active) {
            if (s > mcur) {
                float f = __expf(mcur - s);
                lsum *= f;
                #pragma unroll
                for (int d = 0; d < HD; ++d) oacc[d] *= f;
                mcur = s;
            }
            float p = __expf(s - mcur);
            lsum += p;
            #pragma unroll
            for (int d = 0; d < HD; ++d) oacc[d] += p * vp[d];
        }
    }

    // exact log-sum-exp merge across the wave (mcur=-inf lanes contribute 0)
    float M = wmax64(mcur);
    float sc = (mcur == -INFINITY) ? 0.f : __expf(mcur - M);
    float L = wsum64(lsum * sc);
    float inv = 1.f / L;
    #pragma unroll
    for (int d = 0; d < HD; ++d) {
        float o = wsum64(oacc[d] * sc);
        if (lane == d) att_s[h * HD + lane] = o * inv;  // lanes 0..10 write
    }
    __syncthreads();

    // fused output projection: out[n][j] = bo[j] + sum_k att[k] * Wo[k][j]
    int j = threadIdx.x;
    if (j < HH) {
        float a = bo[j];
        #pragma unroll
        for (int k = 0; k < HH; ++k) a += att_s[k] * Wo[k * HH + j];
        out[(size_t)n * HH + j] = a;
    }
}

extern "C" void kernel_launch(void* const* d_in, const int* in_sizes, int n_in,
                              void* d_out, int out_size, void* d_ws, size_t ws_size,
                              hipStream_t stream) {
    const float* nf       = (const float*)d_in[0];
    const int*   ei       = (const int*)d_in[1];
    const float* temporal = (const float*)d_in[2];
    const float* Wp = (const float*)d_in[3];
    const float* bp = (const float*)d_in[4];
    const float* Wq = (const float*)d_in[5];
    const float* bq = (const float*)d_in[6];
    const float* Wk = (const float*)d_in[7];
    const float* bk = (const float*)d_in[8];
    const float* Wv = (const float*)d_in[9];
    const float* bv = (const float*)d_in[10];
    const float* Wo = (const float*)d_in[11];
    const float* bo = (const float*)d_in[12];
    float* out = (float*)d_out;

    char* ws = (char*)d_ws;
    unsigned long long* mask = (unsigned long long*)ws;        // 2 MB
    int*   cnt  = (int*)(ws + (2u << 20));                     // 16 KB
    int*   cols = cnt + NN;                                    // 8 MB
    float* x    = (float*)(cols + (size_t)NN * CAP);
    float* Qs   = x  + NN * HH;
    float* Ks   = Qs + NN * HH;
    float* Vs   = Ks + NN * HH;

    hipMemsetAsync(mask, 0, NN * MASKW * sizeof(unsigned long long), stream);
    proj_in<<<(NN * HH + 255) / 256, 256, 0, stream>>>(nf, Wp, bp, x);
    build_mask<<<(NEDGE + 255) / 256, 256, 0, stream>>>(ei, mask);
    proj_qkv<<<(NN * HH + 255) / 256, 256, 0, stream>>>(x, Wq, bq, Wk, bk, Wv, bv, Qs, Ks, Vs);
    csr_build<<<NN / 4, 256, 0, stream>>>(mask, cnt, cols);
    attn_out<<<NN, 256, 0, stream>>>(Qs, Ks, Vs, temporal, cnt, cols, Wo, bo, out);
}